// Round 17
// baseline (194.881 us; speedup 1.0000x reference)
//
#include <hip/hip_runtime.h>
#include <hip/hip_fp16.h>
#include <math.h>

#define F_IN   256
#define C1     128   // H1*D1
#define H1N    4
#define D2N    64

#define SCAN_T    256
#define SCAN_TILE 512   // 2 elements per thread

#define BK2 32          // gemm2 K-tile

typedef __attribute__((ext_vector_type(8))) _Float16 f16x8;
typedef __attribute__((ext_vector_type(4))) float    f32x4;

// ---------------- W1 transpose to fp16: W1T[c][k] = (half)W1[k][c] ----------------
__global__ void w1_transpose(const float* __restrict__ W1, __half* __restrict__ W1T) {
    int c = blockIdx.x;                       // 0..127
    for (int k = threadIdx.x; k < F_IN; k += blockDim.x)
        W1T[(size_t)c * F_IN + k] = __float2half(W1[(size_t)k * C1 + c]);
}

// ---------------- standalone: edge count + rank (single histogram) ----------------
__global__ void count_kernel(const int* __restrict__ dst, int* __restrict__ counts,
                             int* __restrict__ edge_rank, int E) {
    int i = blockIdx.x * blockDim.x + threadIdx.x;
    for (; i < E; i += gridDim.x * blockDim.x)
        edge_rank[i] = atomicAdd(&counts[dst[i]], 1);
}

// ---------------- standalone: layer-1 MFMA GEMM (R13/R15 structure) ----------------
// BM=64, BN=128, BK=32; 4 waves; A: x tile fp16 in LDS; B: frags from W1T (L2-resident).
__global__ __launch_bounds__(256) void gemm1_kernel(
        const float* __restrict__ x, const __half* __restrict__ W1T,
        const float* __restrict__ attS, const float* __restrict__ attD,
        __half* __restrict__ hx1h, float* __restrict__ as1, float* __restrict__ ad1,
        int N) {
    __shared__ __half xh[64][40];   // 80B row stride: 16B-aligned, 2-way banks max

    int tid = threadIdx.x;
    int wv  = tid >> 6;             // wave 0..3
    int l   = tid & 63;
    int n0  = blockIdx.x * 64;

    f32x4 acc[8];
#pragma unroll
    for (int t = 0; t < 8; ++t) acc[t] = (f32x4){0.f, 0.f, 0.f, 0.f};

    int srow = tid >> 2;                  // 0..63
    int skg  = (tid & 3) * 8;             // 0,8,16,24
    int xrow = n0 + srow; if (xrow >= N) xrow = N - 1;   // clamp (stores guarded)
    const float* xptr = x + (size_t)xrow * F_IN;

    int arow = wv * 16 + (l & 15);        // A row within block tile
    int akk  = (l >> 4) * 8;              // A k-run
    int bcol = l & 15;                    // B col within 16-col tile
    int bkk  = (l >> 4) * 8;              // B k-run

    for (int s = 0; s < 8; ++s) {
        int k0 = s * 32;
        float4 a0 = *(const float4*)(xptr + k0 + skg);
        float4 a1 = *(const float4*)(xptr + k0 + skg + 4);
        __syncthreads();                  // previous tile consumed
        __half2* dp = (__half2*)&xh[srow][skg];
        dp[0] = __floats2half2_rn(a0.x, a0.y);
        dp[1] = __floats2half2_rn(a0.z, a0.w);
        dp[2] = __floats2half2_rn(a1.x, a1.y);
        dp[3] = __floats2half2_rn(a1.z, a1.w);
        __syncthreads();
        f16x8 af = *reinterpret_cast<const f16x8*>(&xh[arow][akk]);
#pragma unroll
        for (int t = 0; t < 8; ++t) {
            f16x8 bf = *reinterpret_cast<const f16x8*>(
                W1T + (size_t)(16 * t + bcol) * F_IN + k0 + bkk);
            acc[t] = __builtin_amdgcn_mfma_f32_16x16x32_f16(af, bf, acc[t], 0, 0, 0);
        }
    }

    // epilogue: D layout col = l&15, row = 4*(l>>4)+r
    float aS[8], aD[8];
#pragma unroll
    for (int t = 0; t < 8; ++t) {
        aS[t] = attS[16 * t + bcol];
        aD[t] = attD[16 * t + bcol];
    }
#pragma unroll
    for (int r = 0; r < 4; ++r) {
        int n = n0 + wv * 16 + 4 * (l >> 4) + r;
        float ts[4], td[4];
#pragma unroll
        for (int h = 0; h < 4; ++h) {
            ts[h] = acc[2 * h][r] * aS[2 * h] + acc[2 * h + 1][r] * aS[2 * h + 1];
            td[h] = acc[2 * h][r] * aD[2 * h] + acc[2 * h + 1][r] * aD[2 * h + 1];
        }
#pragma unroll
        for (int off = 1; off <= 8; off <<= 1)
#pragma unroll
            for (int h = 0; h < 4; ++h) {
                ts[h] += __shfl_xor(ts[h], off, 64);
                td[h] += __shfl_xor(td[h], off, 64);
            }
        if (n < N) {
#pragma unroll
            for (int t = 0; t < 8; ++t)
                hx1h[(size_t)n * C1 + 16 * t + bcol] = __float2half(acc[t][r]);
            if (bcol == 0) {
#pragma unroll
                for (int h = 0; h < 4; ++h) {
                    as1[n * H1N + h] = ts[h];
                    ad1[n * H1N + h] = td[h];
                }
            }
        }
    }
}

// ---------------- scan: counts -> offsets ----------------
__global__ void scan_partial(const int* __restrict__ counts, int* __restrict__ tilesums, int N) {
    __shared__ int red[SCAN_T];
    int t  = threadIdx.x;
    int i0 = blockIdx.x * SCAN_TILE + 2 * t;
    int s = 0;
    if (i0     < N) s += counts[i0];
    if (i0 + 1 < N) s += counts[i0 + 1];
    red[t] = s;
    __syncthreads();
    for (int off = SCAN_T / 2; off > 0; off >>= 1) {
        if (t < off) red[t] += red[t + off];
        __syncthreads();
    }
    if (t == 0) tilesums[blockIdx.x] = red[0];
}

__global__ void scan_tops(const int* __restrict__ tilesums, int* __restrict__ tilebase, int ntiles) {
    __shared__ int sh[SCAN_T];
    int t = threadIdx.x;
    int v = (t < ntiles) ? tilesums[t] : 0;
    sh[t] = v;
    __syncthreads();
    for (int off = 1; off < SCAN_T; off <<= 1) {
        int u = (t >= off) ? sh[t - off] : 0;
        __syncthreads();
        sh[t] += u;
        __syncthreads();
    }
    tilebase[t] = sh[t] - v;
}

__global__ void scan_final(const int* __restrict__ counts, const int* __restrict__ tilebase,
                           int* __restrict__ offsets, int N, int E) {
    __shared__ int sh[SCAN_T];
    int t  = threadIdx.x;
    int i0 = blockIdx.x * SCAN_TILE + 2 * t;
    int a   = (i0     < N) ? counts[i0]     : 0;
    int b   = (i0 + 1 < N) ? counts[i0 + 1] : 0;
    int tot = a + b;
    sh[t] = tot;
    __syncthreads();
    for (int off = 1; off < SCAN_T; off <<= 1) {
        int u = (t >= off) ? sh[t - off] : 0;
        __syncthreads();
        sh[t] += u;
        __syncthreads();
    }
    int excl = sh[t] - tot + tilebase[blockIdx.x];
    if (i0 < N)     offsets[i0]     = excl;
    if (i0 + 1 < N) offsets[i0 + 1] = excl + a;
    if (blockIdx.x == 0 && t == 0) offsets[N] = E;
}

// ---------------- atomic-free, XCD-binned scatter ----------------
__global__ void scatter_rank(const int* __restrict__ src, const int* __restrict__ dst,
                             const int* __restrict__ edge_rank, const int* __restrict__ offsets,
                             int* __restrict__ edge_src, int E, int N) {
    int grp  = blockIdx.x & 7;
    int gidx = blockIdx.x >> 3;
    int ngrp = gridDim.x >> 3;
    int lo = (int)((long long)N * grp / 8);
    int hi = (int)((long long)N * (grp + 1) / 8);
    for (int i = gidx * blockDim.x + threadIdx.x; i < E; i += ngrp * blockDim.x) {
        int d = dst[i];
        if (d >= lo && d < hi)
            edge_src[offsets[d] + edge_rank[i]] = src[i];
    }
}

// ---------------- layer 1 aggregate: no-max softmax, fp16 gather ----------------
__global__ void agg1_kernel(const int* __restrict__ edge_src, const int* __restrict__ offsets,
                            const float* __restrict__ as1, const float* __restrict__ ad1,
                            const __half* __restrict__ hx1h, const float* __restrict__ b1,
                            float* __restrict__ x1, int N) {
    __shared__ int   ssh[4][64];
    __shared__ float esh[4][64][4];
    int wid  = threadIdx.x >> 6;
    int n    = (blockIdx.x * blockDim.x + threadIdx.x) >> 6;
    int lane = threadIdx.x & 63;
    if (n >= N) return;
    int hsel = lane >> 4;                    // head of cols (2l, 2l+1)
    const float4 ad4 = *(const float4*)(ad1 + 4 * n);
    int beg = offsets[n], end = offsets[n + 1];

    float den[4] = {0.f, 0.f, 0.f, 0.f};
    float acc0 = 0.f, acc1 = 0.f;

    for (int cb = beg; cb < end; cb += 64) {
        int j = cb + lane;
        bool valid = j < end;
        int s = valid ? edge_src[j] : 0;
        float e0 = 0.f, e1 = 0.f, e2 = 0.f, e3 = 0.f;
        if (valid) {
            const float4 a4 = *(const float4*)(as1 + 4 * s);
            float v0 = a4.x + ad4.x, v1 = a4.y + ad4.y;
            float v2 = a4.z + ad4.z, v3 = a4.w + ad4.w;
            v0 = v0 > 0.f ? v0 : 0.2f * v0;
            v1 = v1 > 0.f ? v1 : 0.2f * v1;
            v2 = v2 > 0.f ? v2 : 0.2f * v2;
            v3 = v3 > 0.f ? v3 : 0.2f * v3;
            e0 = __expf(v0); e1 = __expf(v1);
            e2 = __expf(v2); e3 = __expf(v3);
            den[0] += e0; den[1] += e1; den[2] += e2; den[3] += e3;
        }
        ssh[wid][lane] = s;
        *(float4*)&esh[wid][lane][0] = make_float4(e0, e1, e2, e3);

        int cnt = min(64, end - cb);
#pragma unroll 4
        for (int jj = 0; jj < cnt; ++jj) {
            int   sj = ssh[wid][jj];
            float w  = esh[wid][jj][hsel];
            const __half2* hr = (const __half2*)(hx1h + (size_t)sj * C1);
            float2 vf = __half22float2(hr[lane]);
            acc0 += w * vf.x;
            acc1 += w * vf.y;
        }
    }

#pragma unroll
    for (int off = 32; off > 0; off >>= 1)
#pragma unroll
        for (int h = 0; h < 4; ++h) den[h] += __shfl_xor(den[h], off, 64);

    float d = lane < 16 ? den[0] : lane < 32 ? den[1] : lane < 48 ? den[2] : den[3];
    float inv = 1.f / (d + 1e-16f);
    float2 bv = *(const float2*)(b1 + 2 * lane);
    float o0 = acc0 * inv + bv.x;
    float o1 = acc1 * inv + bv.y;
    o0 = o0 > 0.f ? o0 : (__expf(o0) - 1.f);   // ELU
    o1 = o1 > 0.f ? o1 : (__expf(o1) - 1.f);
    *(float2*)&x1[(size_t)n * C1 + 2 * lane] = make_float2(o0, o1);
}

// ---------------- layer 2 GEMM: hx2 = x1 @ W2 (+ logits), register-tiled ----------------
__global__ __launch_bounds__(256) void gemm2_kernel(
        const float* __restrict__ x1, const float* __restrict__ W2,
        const float* __restrict__ attS, const float* __restrict__ attD,
        float* __restrict__ hx2, float* __restrict__ as2, float* __restrict__ ad2,
        int N) {
    __shared__ float xT[BK2][64 + 4];
    __shared__ float ws2[BK2][D2N];

    int tid = threadIdx.x;
    int tx  = tid & 15;
    int ty  = tid >> 4;
    int n0  = blockIdx.x * 64;

    float acc[4][4];
#pragma unroll
    for (int r = 0; r < 4; ++r)
#pragma unroll
        for (int c = 0; c < 4; ++c) acc[r][c] = 0.f;

    int lr = tid >> 2;
    int lk = (tid & 3) * 4;
    int xrow = n0 + lr; if (xrow >= N) xrow = N - 1;
    const float* xptr = x1 + (size_t)xrow * C1;
    int kw = tid >> 4;
    int cw = tx * 4;

    for (int k0 = 0; k0 < C1; k0 += BK2) {
        float4 a0 = *(const float4*)(xptr + k0 + lk);
        float4 a1 = *(const float4*)(xptr + k0 + lk + 16);
        float4 w0 = *(const float4*)(W2 + (size_t)(k0 + kw     ) * D2N + cw);
        float4 w1 = *(const float4*)(W2 + (size_t)(k0 + kw + 16) * D2N + cw);
        __syncthreads();
        xT[lk + 0][lr] = a0.x; xT[lk + 1][lr] = a0.y;
        xT[lk + 2][lr] = a0.z; xT[lk + 3][lr] = a0.w;
        xT[lk + 16][lr] = a1.x; xT[lk + 17][lr] = a1.y;
        xT[lk + 18][lr] = a1.z; xT[lk + 19][lr] = a1.w;
        *(float4*)&ws2[kw     ][cw] = w0;
        *(float4*)&ws2[kw + 16][cw] = w1;
        __syncthreads();
#pragma unroll
        for (int k = 0; k < BK2; ++k) {
            float4 xa = *(const float4*)&xT[k][ty * 4];
            float4 wv = *(const float4*)&ws2[k][tx * 4];
            float xr[4] = {xa.x, xa.y, xa.z, xa.w};
            float wc[4] = {wv.x, wv.y, wv.z, wv.w};
#pragma unroll
            for (int r = 0; r < 4; ++r)
#pragma unroll
                for (int c = 0; c < 4; ++c) acc[r][c] += xr[r] * wc[c];
        }
    }

    const float4 asv = *(const float4*)(attS + tx * 4);
    const float4 adv = *(const float4*)(attD + tx * 4);
#pragma unroll
    for (int r = 0; r < 4; ++r) {
        int n = n0 + ty * 4 + r;
        float ts = acc[r][0] * asv.x + acc[r][1] * asv.y + acc[r][2] * asv.z + acc[r][3] * asv.w;
        float td = acc[r][0] * adv.x + acc[r][1] * adv.y + acc[r][2] * adv.z + acc[r][3] * adv.w;
        ts += __shfl_xor(ts, 1); td += __shfl_xor(td, 1);
        ts += __shfl_xor(ts, 2); td += __shfl_xor(td, 2);
        ts += __shfl_xor(ts, 4); td += __shfl_xor(td, 4);
        ts += __shfl_xor(ts, 8); td += __shfl_xor(td, 8);
        if (n < N) {
            *(float4*)&hx2[(size_t)n * D2N + tx * 4] =
                make_float4(acc[r][0], acc[r][1], acc[r][2], acc[r][3]);
            if (tx == 0) { as2[n] = ts; ad2[n] = td; }
        }
    }
}

// ---------------- layer 2 aggregate: no-max softmax, only last num_new nodes ----------------
__global__ void agg2_kernel(const int* __restrict__ edge_src, const int* __restrict__ offsets,
                            const float* __restrict__ as2, const float* __restrict__ ad2,
                            const float* __restrict__ hx2, const float* __restrict__ b2,
                            float* __restrict__ out, int N, int num_new) {
    __shared__ int   ssh[4][64];
    __shared__ float esh[4][64];
    int wid  = threadIdx.x >> 6;
    int w    = (blockIdx.x * blockDim.x + threadIdx.x) >> 6;
    int lane = threadIdx.x & 63;
    if (w >= num_new) return;
    int n = N - num_new + w;
    float adn = ad2[n];
    int beg = offsets[n], end = offsets[n + 1];

    float den = 0.f, acc = 0.f;
    for (int cb = beg; cb < end; cb += 64) {
        int j = cb + lane;
        bool valid = j < end;
        int s = valid ? edge_src[j] : 0;
        float e = 0.f;
        if (valid) {
            float v = as2[s] + adn;
            v = v > 0.f ? v : 0.2f * v;
            e = __expf(v);
            den += e;
        }
        ssh[wid][lane] = s;
        esh[wid][lane] = e;

        int cnt = min(64, end - cb);
#pragma unroll 4
        for (int jj = 0; jj < cnt; ++jj) {
            int   sj = ssh[wid][jj];
            float wj = esh[wid][jj];
            acc += wj * hx2[(size_t)sj * D2N + lane];
        }
    }
#pragma unroll
    for (int off = 32; off > 0; off >>= 1) den += __shfl_xor(den, off, 64);
    out[(size_t)w * D2N + lane] = acc / (den + 1e-16f) + b2[lane];
}

// ---------------- launch ----------------
extern "C" void kernel_launch(void* const* d_in, const int* in_sizes, int n_in,
                              void* d_out, int out_size, void* d_ws, size_t ws_size,
                              hipStream_t stream) {
    const float* x      = (const float*)d_in[0];
    const int*   src    = (const int*)d_in[1];
    const int*   dst    = (const int*)d_in[2];
    const float* W1     = (const float*)d_in[3];
    const float* attS1  = (const float*)d_in[4];
    const float* attD1  = (const float*)d_in[5];
    const float* b1     = (const float*)d_in[6];
    const float* W2     = (const float*)d_in[7];
    const float* attS2  = (const float*)d_in[8];
    const float* attD2  = (const float*)d_in[9];
    const float* b2     = (const float*)d_in[10];

    const int N = in_sizes[0] / F_IN;   // 50000
    const int E = in_sizes[1];          // 1000000
    const int num_new = out_size / D2N; // 10000
    const int ntiles = (N + SCAN_TILE - 1) / SCAN_TILE;   // 98
    const int ngemm  = (N + 63) / 64;                     // 782

    // workspace carve-up
    __half* hx1h = (__half*)d_ws;                        // N*128 halves
    float* x1  = (float*)(hx1h + (size_t)N * C1);        // N*128 f32
    float* hx2 = x1  + (size_t)N * C1;                   // N*64
    float* as1 = hx2 + (size_t)N * D2N;                  // N*4
    float* ad1 = as1 + (size_t)N * H1N;                  // N*4
    float* as2 = ad1 + (size_t)N * H1N;                  // N
    float* ad2 = as2 + N;                                // N
    int* counts    = (int*)(ad2 + N);                    // N
    int* offsets   = counts + N;                         // N+1
    int* tilesums  = offsets + N + 1;                    // 256
    int* tilebase  = tilesums + 256;                     // 256
    int* edge_src  = tilebase + 256;                     // E
    int* edge_rank = edge_src + E;                       // E
    __half* W1T    = (__half*)(edge_rank + E);           // 128*256 halves

    float* out = (float*)d_out;

    hipMemsetAsync(counts, 0, (size_t)N * sizeof(int), stream);
    hipLaunchKernelGGL(w1_transpose, dim3(C1), dim3(256), 0, stream, W1, W1T);
    hipLaunchKernelGGL(count_kernel, dim3(2048), dim3(256), 0, stream,
                       dst, counts, edge_rank, E);
    hipLaunchKernelGGL(gemm1_kernel, dim3(ngemm), dim3(256), 0, stream,
                       x, W1T, attS1, attD1, hx1h, as1, ad1, N);
    hipLaunchKernelGGL(scan_partial, dim3(ntiles), dim3(SCAN_T), 0, stream, counts, tilesums, N);
    hipLaunchKernelGGL(scan_tops, dim3(1), dim3(SCAN_T), 0, stream, tilesums, tilebase, ntiles);
    hipLaunchKernelGGL(scan_final, dim3(ntiles), dim3(SCAN_T), 0, stream,
                       counts, tilebase, offsets, N, E);
    hipLaunchKernelGGL(scatter_rank, dim3(2048), dim3(256), 0, stream,
                       src, dst, edge_rank, offsets, edge_src, E, N);
    hipLaunchKernelGGL(agg1_kernel, dim3((N + 3) / 4), dim3(256), 0, stream,
                       edge_src, offsets, as1, ad1, hx1h, b1, x1, N);
    hipLaunchKernelGGL(gemm2_kernel, dim3((N + 63) / 64), dim3(256), 0, stream,
                       x1, W2, attS2, attD2, hx2, as2, ad2, N);
    hipLaunchKernelGGL(agg2_kernel, dim3((num_new + 3) / 4), dim3(256), 0, stream,
                       edge_src, offsets, as2, ad2, hx2, b2, out, N, num_new);
}

// Round 18
// 164.070 us; speedup vs baseline: 1.1878x; 1.1878x over previous
//
#include <hip/hip_runtime.h>
#include <hip/hip_fp16.h>
#include <math.h>

#define F_IN   256
#define C1     128   // H1*D1
#define H1N    4
#define D2N    64

#define SCAN_T    256
#define SCAN_TILE 512   // 2 elements per thread

#define BK2 32          // gemm2 K-tile

#define NBLK_P 256      // partition blocks
#define NBUK_MAX 256    // max coarse buckets (dst >> 8)

typedef __attribute__((ext_vector_type(8))) _Float16 f16x8;
typedef __attribute__((ext_vector_type(4))) float    f32x4;

// ---------------- W1 transpose to fp16: W1T[c][k] = (half)W1[k][c] ----------------
__global__ void w1_transpose(const float* __restrict__ W1, __half* __restrict__ W1T) {
    int c = blockIdx.x;                       // 0..127
    for (int k = threadIdx.x; k < F_IN; k += blockDim.x)
        W1T[(size_t)c * F_IN + k] = __float2half(W1[(size_t)k * C1 + c]);
}

// ---------------- CSR build pass A: per-block LDS histogram of coarse buckets ----------------
__global__ void part_hist(const int* __restrict__ dst, int* __restrict__ bcounts,
                          int E, int chunk, int nbuk) {
    __shared__ int h[NBUK_MAX];
    for (int t = threadIdx.x; t < nbuk; t += blockDim.x) h[t] = 0;
    __syncthreads();
    int lo = blockIdx.x * chunk, hi = min(lo + chunk, E);
    for (int i = lo + threadIdx.x; i < hi; i += blockDim.x)
        atomicAdd(&h[dst[i] >> 8], 1);                 // LDS atomic
    __syncthreads();
    for (int t = threadIdx.x; t < nbuk; t += blockDim.x)
        bcounts[(size_t)t * NBLK_P + blockIdx.x] = h[t];
}

// ---------------- CSR build pass C: partition edges into bucket order ----------------
__global__ void part_scatter(const int* __restrict__ src, const int* __restrict__ dst,
                             const int* __restrict__ bbase, int2* __restrict__ pedge,
                             int E, int chunk, int nbuk) {
    __shared__ int cur[NBUK_MAX];
    for (int t = threadIdx.x; t < nbuk; t += blockDim.x)
        cur[t] = bbase[(size_t)t * NBLK_P + blockIdx.x];
    __syncthreads();
    int lo = blockIdx.x * chunk, hi = min(lo + chunk, E);
    for (int i = lo + threadIdx.x; i < hi; i += blockDim.x) {
        int d = dst[i];
        int p = atomicAdd(&cur[d >> 8], 1);            // LDS atomic
        pedge[p] = make_int2(src[i], d);
    }
}

// ---------------- CSR build pass D: per-bucket fine CSR (256 nodes/bucket) ----------------
__global__ __launch_bounds__(256) void part_csr(
        const int2* __restrict__ pedge, const int* __restrict__ bbase,
        int* __restrict__ offsets, int* __restrict__ edge_src,
        int N, int E, int nbuk) {
    __shared__ int fcnt[256];
    __shared__ int fsc[256];
    int b = blockIdx.x;
    int t = threadIdx.x;
    int ebeg = bbase[(size_t)b * NBLK_P];
    int eend = (b + 1 < nbuk) ? bbase[(size_t)(b + 1) * NBLK_P] : E;
    int nbase = b << 8;
    fcnt[t] = 0;
    __syncthreads();
    for (int i = ebeg + t; i < eend; i += 256)
        atomicAdd(&fcnt[pedge[i].y - nbase], 1);       // LDS atomic
    __syncthreads();
    int v = fcnt[t];
    fsc[t] = v;
    __syncthreads();
    for (int off = 1; off < 256; off <<= 1) {
        int u = (t >= off) ? fsc[t - off] : 0;
        __syncthreads();
        fsc[t] += u;
        __syncthreads();
    }
    int goff = ebeg + fsc[t] - v;                      // global CSR start of node nbase+t
    int node = nbase + t;
    if (node < N) offsets[node] = goff;
    if (b == nbuk - 1 && t == 0) offsets[N] = E;
    __syncthreads();
    fcnt[t] = goff;                                    // reuse as cursor
    __syncthreads();
    for (int i = ebeg + t; i < eend; i += 256) {
        int2 e = pedge[i];
        int p = atomicAdd(&fcnt[e.y - nbase], 1);      // LDS atomic
        edge_src[p] = e.x;
    }
}

// ---------------- standalone: layer-1 MFMA GEMM (R13/R15 structure) ----------------
__global__ __launch_bounds__(256) void gemm1_kernel(
        const float* __restrict__ x, const __half* __restrict__ W1T,
        const float* __restrict__ attS, const float* __restrict__ attD,
        __half* __restrict__ hx1h, float* __restrict__ as1, float* __restrict__ ad1,
        int N) {
    __shared__ __half xh[64][40];   // 80B row stride: 16B-aligned, 2-way banks max

    int tid = threadIdx.x;
    int wv  = tid >> 6;             // wave 0..3
    int l   = tid & 63;
    int n0  = blockIdx.x * 64;

    f32x4 acc[8];
#pragma unroll
    for (int t = 0; t < 8; ++t) acc[t] = (f32x4){0.f, 0.f, 0.f, 0.f};

    int srow = tid >> 2;                  // 0..63
    int skg  = (tid & 3) * 8;             // 0,8,16,24
    int xrow = n0 + srow; if (xrow >= N) xrow = N - 1;   // clamp (stores guarded)
    const float* xptr = x + (size_t)xrow * F_IN;

    int arow = wv * 16 + (l & 15);        // A row within block tile
    int akk  = (l >> 4) * 8;              // A k-run
    int bcol = l & 15;                    // B col within 16-col tile
    int bkk  = (l >> 4) * 8;              // B k-run

    for (int s = 0; s < 8; ++s) {
        int k0 = s * 32;
        float4 a0 = *(const float4*)(xptr + k0 + skg);
        float4 a1 = *(const float4*)(xptr + k0 + skg + 4);
        __syncthreads();                  // previous tile consumed
        __half2* dp = (__half2*)&xh[srow][skg];
        dp[0] = __floats2half2_rn(a0.x, a0.y);
        dp[1] = __floats2half2_rn(a0.z, a0.w);
        dp[2] = __floats2half2_rn(a1.x, a1.y);
        dp[3] = __floats2half2_rn(a1.z, a1.w);
        __syncthreads();
        f16x8 af = *reinterpret_cast<const f16x8*>(&xh[arow][akk]);
#pragma unroll
        for (int t = 0; t < 8; ++t) {
            f16x8 bf = *reinterpret_cast<const f16x8*>(
                W1T + (size_t)(16 * t + bcol) * F_IN + k0 + bkk);
            acc[t] = __builtin_amdgcn_mfma_f32_16x16x32_f16(af, bf, acc[t], 0, 0, 0);
        }
    }

    // epilogue: D layout col = l&15, row = 4*(l>>4)+r
    float aS[8], aD[8];
#pragma unroll
    for (int t = 0; t < 8; ++t) {
        aS[t] = attS[16 * t + bcol];
        aD[t] = attD[16 * t + bcol];
    }
#pragma unroll
    for (int r = 0; r < 4; ++r) {
        int n = n0 + wv * 16 + 4 * (l >> 4) + r;
        float ts[4], td[4];
#pragma unroll
        for (int h = 0; h < 4; ++h) {
            ts[h] = acc[2 * h][r] * aS[2 * h] + acc[2 * h + 1][r] * aS[2 * h + 1];
            td[h] = acc[2 * h][r] * aD[2 * h] + acc[2 * h + 1][r] * aD[2 * h + 1];
        }
#pragma unroll
        for (int off = 1; off <= 8; off <<= 1)
#pragma unroll
            for (int h = 0; h < 4; ++h) {
                ts[h] += __shfl_xor(ts[h], off, 64);
                td[h] += __shfl_xor(td[h], off, 64);
            }
        if (n < N) {
#pragma unroll
            for (int t = 0; t < 8; ++t)
                hx1h[(size_t)n * C1 + 16 * t + bcol] = __float2half(acc[t][r]);
            if (bcol == 0) {
#pragma unroll
                for (int h = 0; h < 4; ++h) {
                    as1[n * H1N + h] = ts[h];
                    ad1[n * H1N + h] = td[h];
                }
            }
        }
    }
}

// ---------------- scan: generic hierarchical exclusive scan (counts[M] -> base[M+1]) ----------------
__global__ void scan_partial(const int* __restrict__ counts, int* __restrict__ tilesums, int N) {
    __shared__ int red[SCAN_T];
    int t  = threadIdx.x;
    int i0 = blockIdx.x * SCAN_TILE + 2 * t;
    int s = 0;
    if (i0     < N) s += counts[i0];
    if (i0 + 1 < N) s += counts[i0 + 1];
    red[t] = s;
    __syncthreads();
    for (int off = SCAN_T / 2; off > 0; off >>= 1) {
        if (t < off) red[t] += red[t + off];
        __syncthreads();
    }
    if (t == 0) tilesums[blockIdx.x] = red[0];
}

__global__ void scan_tops(const int* __restrict__ tilesums, int* __restrict__ tilebase, int ntiles) {
    __shared__ int sh[SCAN_T];
    int t = threadIdx.x;
    int v = (t < ntiles) ? tilesums[t] : 0;
    sh[t] = v;
    __syncthreads();
    for (int off = 1; off < SCAN_T; off <<= 1) {
        int u = (t >= off) ? sh[t - off] : 0;
        __syncthreads();
        sh[t] += u;
        __syncthreads();
    }
    tilebase[t] = sh[t] - v;
}

__global__ void scan_final(const int* __restrict__ counts, const int* __restrict__ tilebase,
                           int* __restrict__ base, int N, int E) {
    __shared__ int sh[SCAN_T];
    int t  = threadIdx.x;
    int i0 = blockIdx.x * SCAN_TILE + 2 * t;
    int a   = (i0     < N) ? counts[i0]     : 0;
    int b   = (i0 + 1 < N) ? counts[i0 + 1] : 0;
    int tot = a + b;
    sh[t] = tot;
    __syncthreads();
    for (int off = 1; off < SCAN_T; off <<= 1) {
        int u = (t >= off) ? sh[t - off] : 0;
        __syncthreads();
        sh[t] += u;
        __syncthreads();
    }
    int excl = sh[t] - tot + tilebase[blockIdx.x];
    if (i0 < N)     base[i0]     = excl;
    if (i0 + 1 < N) base[i0 + 1] = excl + a;
    if (blockIdx.x == 0 && t == 0) base[N] = E;
}

// ---------------- layer 1 aggregate: no-max softmax, fp16 gather ----------------
__global__ void agg1_kernel(const int* __restrict__ edge_src, const int* __restrict__ offsets,
                            const float* __restrict__ as1, const float* __restrict__ ad1,
                            const __half* __restrict__ hx1h, const float* __restrict__ b1,
                            float* __restrict__ x1, int N) {
    __shared__ int   ssh[4][64];
    __shared__ float esh[4][64][4];
    int wid  = threadIdx.x >> 6;
    int n    = (blockIdx.x * blockDim.x + threadIdx.x) >> 6;
    int lane = threadIdx.x & 63;
    if (n >= N) return;
    int hsel = lane >> 4;                    // head of cols (2l, 2l+1)
    const float4 ad4 = *(const float4*)(ad1 + 4 * n);
    int beg = offsets[n], end = offsets[n + 1];

    float den[4] = {0.f, 0.f, 0.f, 0.f};
    float acc0 = 0.f, acc1 = 0.f;

    for (int cb = beg; cb < end; cb += 64) {
        int j = cb + lane;
        bool valid = j < end;
        int s = valid ? edge_src[j] : 0;
        float e0 = 0.f, e1 = 0.f, e2 = 0.f, e3 = 0.f;
        if (valid) {
            const float4 a4 = *(const float4*)(as1 + 4 * s);
            float v0 = a4.x + ad4.x, v1 = a4.y + ad4.y;
            float v2 = a4.z + ad4.z, v3 = a4.w + ad4.w;
            v0 = v0 > 0.f ? v0 : 0.2f * v0;
            v1 = v1 > 0.f ? v1 : 0.2f * v1;
            v2 = v2 > 0.f ? v2 : 0.2f * v2;
            v3 = v3 > 0.f ? v3 : 0.2f * v3;
            e0 = __expf(v0); e1 = __expf(v1);
            e2 = __expf(v2); e3 = __expf(v3);
            den[0] += e0; den[1] += e1; den[2] += e2; den[3] += e3;
        }
        ssh[wid][lane] = s;
        *(float4*)&esh[wid][lane][0] = make_float4(e0, e1, e2, e3);

        int cnt = min(64, end - cb);
#pragma unroll 4
        for (int jj = 0; jj < cnt; ++jj) {
            int   sj = ssh[wid][jj];
            float w  = esh[wid][jj][hsel];
            const __half2* hr = (const __half2*)(hx1h + (size_t)sj * C1);
            float2 vf = __half22float2(hr[lane]);
            acc0 += w * vf.x;
            acc1 += w * vf.y;
        }
    }

#pragma unroll
    for (int off = 32; off > 0; off >>= 1)
#pragma unroll
        for (int h = 0; h < 4; ++h) den[h] += __shfl_xor(den[h], off, 64);

    float d = lane < 16 ? den[0] : lane < 32 ? den[1] : lane < 48 ? den[2] : den[3];
    float inv = 1.f / (d + 1e-16f);
    float2 bv = *(const float2*)(b1 + 2 * lane);
    float o0 = acc0 * inv + bv.x;
    float o1 = acc1 * inv + bv.y;
    o0 = o0 > 0.f ? o0 : (__expf(o0) - 1.f);   // ELU
    o1 = o1 > 0.f ? o1 : (__expf(o1) - 1.f);
    *(float2*)&x1[(size_t)n * C1 + 2 * lane] = make_float2(o0, o1);
}

// ---------------- layer 2 GEMM: hx2 = x1 @ W2 (+ logits), register-tiled ----------------
__global__ __launch_bounds__(256) void gemm2_kernel(
        const float* __restrict__ x1, const float* __restrict__ W2,
        const float* __restrict__ attS, const float* __restrict__ attD,
        float* __restrict__ hx2, float* __restrict__ as2, float* __restrict__ ad2,
        int N) {
    __shared__ float xT[BK2][64 + 4];
    __shared__ float ws2[BK2][D2N];

    int tid = threadIdx.x;
    int tx  = tid & 15;
    int ty  = tid >> 4;
    int n0  = blockIdx.x * 64;

    float acc[4][4];
#pragma unroll
    for (int r = 0; r < 4; ++r)
#pragma unroll
        for (int c = 0; c < 4; ++c) acc[r][c] = 0.f;

    int lr = tid >> 2;
    int lk = (tid & 3) * 4;
    int xrow = n0 + lr; if (xrow >= N) xrow = N - 1;
    const float* xptr = x1 + (size_t)xrow * C1;
    int kw = tid >> 4;
    int cw = tx * 4;

    for (int k0 = 0; k0 < C1; k0 += BK2) {
        float4 a0 = *(const float4*)(xptr + k0 + lk);
        float4 a1 = *(const float4*)(xptr + k0 + lk + 16);
        float4 w0 = *(const float4*)(W2 + (size_t)(k0 + kw     ) * D2N + cw);
        float4 w1 = *(const float4*)(W2 + (size_t)(k0 + kw + 16) * D2N + cw);
        __syncthreads();
        xT[lk + 0][lr] = a0.x; xT[lk + 1][lr] = a0.y;
        xT[lk + 2][lr] = a0.z; xT[lk + 3][lr] = a0.w;
        xT[lk + 16][lr] = a1.x; xT[lk + 17][lr] = a1.y;
        xT[lk + 18][lr] = a1.z; xT[lk + 19][lr] = a1.w;
        *(float4*)&ws2[kw     ][cw] = w0;
        *(float4*)&ws2[kw + 16][cw] = w1;
        __syncthreads();
#pragma unroll
        for (int k = 0; k < BK2; ++k) {
            float4 xa = *(const float4*)&xT[k][ty * 4];
            float4 wv = *(const float4*)&ws2[k][tx * 4];
            float xr[4] = {xa.x, xa.y, xa.z, xa.w};
            float wc[4] = {wv.x, wv.y, wv.z, wv.w};
#pragma unroll
            for (int r = 0; r < 4; ++r)
#pragma unroll
                for (int c = 0; c < 4; ++c) acc[r][c] += xr[r] * wc[c];
        }
    }

    const float4 asv = *(const float4*)(attS + tx * 4);
    const float4 adv = *(const float4*)(attD + tx * 4);
#pragma unroll
    for (int r = 0; r < 4; ++r) {
        int n = n0 + ty * 4 + r;
        float ts = acc[r][0] * asv.x + acc[r][1] * asv.y + acc[r][2] * asv.z + acc[r][3] * asv.w;
        float td = acc[r][0] * adv.x + acc[r][1] * adv.y + acc[r][2] * adv.z + acc[r][3] * adv.w;
        ts += __shfl_xor(ts, 1); td += __shfl_xor(td, 1);
        ts += __shfl_xor(ts, 2); td += __shfl_xor(td, 2);
        ts += __shfl_xor(ts, 4); td += __shfl_xor(td, 4);
        ts += __shfl_xor(ts, 8); td += __shfl_xor(td, 8);
        if (n < N) {
            *(float4*)&hx2[(size_t)n * D2N + tx * 4] =
                make_float4(acc[r][0], acc[r][1], acc[r][2], acc[r][3]);
            if (tx == 0) { as2[n] = ts; ad2[n] = td; }
        }
    }
}

// ---------------- layer 2 aggregate: no-max softmax, only last num_new nodes ----------------
__global__ void agg2_kernel(const int* __restrict__ edge_src, const int* __restrict__ offsets,
                            const float* __restrict__ as2, const float* __restrict__ ad2,
                            const float* __restrict__ hx2, const float* __restrict__ b2,
                            float* __restrict__ out, int N, int num_new) {
    __shared__ int   ssh[4][64];
    __shared__ float esh[4][64];
    int wid  = threadIdx.x >> 6;
    int w    = (blockIdx.x * blockDim.x + threadIdx.x) >> 6;
    int lane = threadIdx.x & 63;
    if (w >= num_new) return;
    int n = N - num_new + w;
    float adn = ad2[n];
    int beg = offsets[n], end = offsets[n + 1];

    float den = 0.f, acc = 0.f;
    for (int cb = beg; cb < end; cb += 64) {
        int j = cb + lane;
        bool valid = j < end;
        int s = valid ? edge_src[j] : 0;
        float e = 0.f;
        if (valid) {
            float v = as2[s] + adn;
            v = v > 0.f ? v : 0.2f * v;
            e = __expf(v);
            den += e;
        }
        ssh[wid][lane] = s;
        esh[wid][lane] = e;

        int cnt = min(64, end - cb);
#pragma unroll 4
        for (int jj = 0; jj < cnt; ++jj) {
            int   sj = ssh[wid][jj];
            float wj = esh[wid][jj];
            acc += wj * hx2[(size_t)sj * D2N + lane];
        }
    }
#pragma unroll
    for (int off = 32; off > 0; off >>= 1) den += __shfl_xor(den, off, 64);
    out[(size_t)w * D2N + lane] = acc / (den + 1e-16f) + b2[lane];
}

// ---------------- launch ----------------
extern "C" void kernel_launch(void* const* d_in, const int* in_sizes, int n_in,
                              void* d_out, int out_size, void* d_ws, size_t ws_size,
                              hipStream_t stream) {
    const float* x      = (const float*)d_in[0];
    const int*   src    = (const int*)d_in[1];
    const int*   dst    = (const int*)d_in[2];
    const float* W1     = (const float*)d_in[3];
    const float* attS1  = (const float*)d_in[4];
    const float* attD1  = (const float*)d_in[5];
    const float* b1     = (const float*)d_in[6];
    const float* W2     = (const float*)d_in[7];
    const float* attS2  = (const float*)d_in[8];
    const float* attD2  = (const float*)d_in[9];
    const float* b2     = (const float*)d_in[10];

    const int N = in_sizes[0] / F_IN;   // 50000
    const int E = in_sizes[1];          // 1000000
    const int num_new = out_size / D2N; // 10000
    const int ngemm  = (N + 63) / 64;                     // 782
    const int nbuk   = (N + 255) >> 8;                    // 196
    const int M      = nbuk * NBLK_P;                     // 50176
    const int ntilesM = (M + SCAN_TILE - 1) / SCAN_TILE;  // 98
    const int chunk  = (E + NBLK_P - 1) / NBLK_P;         // 3907

    // workspace carve-up
    __half* hx1h = (__half*)d_ws;                        // N*128 halves
    float* x1  = (float*)(hx1h + (size_t)N * C1);        // N*128 f32
    float* hx2 = x1  + (size_t)N * C1;                   // N*64
    float* as1 = hx2 + (size_t)N * D2N;                  // N*4
    float* ad1 = as1 + (size_t)N * H1N;                  // N*4
    float* as2 = ad1 + (size_t)N * H1N;                  // N
    float* ad2 = as2 + N;                                // N
    int* bcounts  = (int*)(ad2 + N);                     // M
    int* bbase    = bcounts + M;                         // M+1
    int* offsets  = bbase + M + 1;                       // N+1
    int* tilesums = offsets + N + 1;                     // 256
    int* tilebase = tilesums + 256;                      // 256
    int* edge_src = tilebase + 256;                      // E
    int2* pedge   = (int2*)(edge_src + E);               // E int2
    __half* W1T   = (__half*)(pedge + E);                // 128*256 halves

    float* out = (float*)d_out;

    hipLaunchKernelGGL(w1_transpose, dim3(C1), dim3(256), 0, stream, W1, W1T);
    hipLaunchKernelGGL(part_hist, dim3(NBLK_P), dim3(256), 0, stream,
                       dst, bcounts, E, chunk, nbuk);
    hipLaunchKernelGGL(gemm1_kernel, dim3(ngemm), dim3(256), 0, stream,
                       x, W1T, attS1, attD1, hx1h, as1, ad1, N);
    hipLaunchKernelGGL(scan_partial, dim3(ntilesM), dim3(SCAN_T), 0, stream, bcounts, tilesums, M);
    hipLaunchKernelGGL(scan_tops, dim3(1), dim3(SCAN_T), 0, stream, tilesums, tilebase, ntilesM);
    hipLaunchKernelGGL(scan_final, dim3(ntilesM), dim3(SCAN_T), 0, stream,
                       bcounts, tilebase, bbase, M, E);
    hipLaunchKernelGGL(part_scatter, dim3(NBLK_P), dim3(256), 0, stream,
                       src, dst, bbase, pedge, E, chunk, nbuk);
    hipLaunchKernelGGL(part_csr, dim3(nbuk), dim3(256), 0, stream,
                       pedge, bbase, offsets, edge_src, N, E, nbuk);
    hipLaunchKernelGGL(agg1_kernel, dim3((N + 3) / 4), dim3(256), 0, stream,
                       edge_src, offsets, as1, ad1, hx1h, b1, x1, N);
    hipLaunchKernelGGL(gemm2_kernel, dim3((N + 63) / 64), dim3(256), 0, stream,
                       x1, W2, attS2, attD2, hx2, as2, ad2, N);
    hipLaunchKernelGGL(agg2_kernel, dim3((num_new + 3) / 4), dim3(256), 0, stream,
                       edge_src, offsets, as2, ad2, hx2, b2, out, N, num_new);
}

// Round 19
// 151.470 us; speedup vs baseline: 1.2866x; 1.0832x over previous
//
#include <hip/hip_runtime.h>
#include <hip/hip_fp16.h>
#include <math.h>

#define F_IN   256
#define C1     128   // H1*D1
#define H1N    4
#define D2N    64

#define SCAN_T    256
#define SCAN_TILE 512   // 2 elements per thread

#define BK2 32          // gemm2 K-tile

#define NBLK_P 256      // partition blocks
#define NBUK_MAX 256    // max coarse buckets (dst >> 8)

typedef __attribute__((ext_vector_type(8))) _Float16 f16x8;
typedef __attribute__((ext_vector_type(4))) float    f32x4;

// ---------------- W1 transpose to fp16: W1T[c][k] = (half)W1[k][c] ----------------
__global__ void w1_transpose(const float* __restrict__ W1, __half* __restrict__ W1T) {
    int c = blockIdx.x;                       // 0..127
    for (int k = threadIdx.x; k < F_IN; k += blockDim.x)
        W1T[(size_t)c * F_IN + k] = __float2half(W1[(size_t)k * C1 + c]);
}

// ---------------- fused: layer-1 MFMA GEMM (blocks < ngemm) + bucket histogram ----------------
__global__ __launch_bounds__(256) void gemm1_hist_kernel(
        const float* __restrict__ x, const __half* __restrict__ W1T,
        const float* __restrict__ attS, const float* __restrict__ attD,
        __half* __restrict__ hx1h, float* __restrict__ as1, float* __restrict__ ad1,
        int N,
        const int* __restrict__ dst, int* __restrict__ bcounts,
        int E, int chunk, int nbuk, int ngemm) {
    if ((int)blockIdx.x >= ngemm) {
        __shared__ int h[NBUK_MAX];
        int b = blockIdx.x - ngemm;           // 0..NBLK_P-1
        for (int t = threadIdx.x; t < nbuk; t += blockDim.x) h[t] = 0;
        __syncthreads();
        int lo = b * chunk, hi = min(lo + chunk, E);
        for (int i = lo + threadIdx.x; i < hi; i += blockDim.x)
            atomicAdd(&h[dst[i] >> 8], 1);                 // LDS atomic
        __syncthreads();
        for (int t = threadIdx.x; t < nbuk; t += blockDim.x)
            bcounts[(size_t)t * NBLK_P + b] = h[t];
        return;
    }

    __shared__ __half xh[64][40];   // 80B row stride: 16B-aligned, 2-way banks max

    int tid = threadIdx.x;
    int wv  = tid >> 6;             // wave 0..3
    int l   = tid & 63;
    int n0  = blockIdx.x * 64;

    f32x4 acc[8];
#pragma unroll
    for (int t = 0; t < 8; ++t) acc[t] = (f32x4){0.f, 0.f, 0.f, 0.f};

    int srow = tid >> 2;                  // 0..63
    int skg  = (tid & 3) * 8;             // 0,8,16,24
    int xrow = n0 + srow; if (xrow >= N) xrow = N - 1;   // clamp (stores guarded)
    const float* xptr = x + (size_t)xrow * F_IN;

    int arow = wv * 16 + (l & 15);        // A row within block tile
    int akk  = (l >> 4) * 8;              // A k-run
    int bcol = l & 15;                    // B col within 16-col tile
    int bkk  = (l >> 4) * 8;              // B k-run

    for (int s = 0; s < 8; ++s) {
        int k0 = s * 32;
        float4 a0 = *(const float4*)(xptr + k0 + skg);
        float4 a1 = *(const float4*)(xptr + k0 + skg + 4);
        __syncthreads();                  // previous tile consumed
        __half2* dp = (__half2*)&xh[srow][skg];
        dp[0] = __floats2half2_rn(a0.x, a0.y);
        dp[1] = __floats2half2_rn(a0.z, a0.w);
        dp[2] = __floats2half2_rn(a1.x, a1.y);
        dp[3] = __floats2half2_rn(a1.z, a1.w);
        __syncthreads();
        f16x8 af = *reinterpret_cast<const f16x8*>(&xh[arow][akk]);
#pragma unroll
        for (int t = 0; t < 8; ++t) {
            f16x8 bf = *reinterpret_cast<const f16x8*>(
                W1T + (size_t)(16 * t + bcol) * F_IN + k0 + bkk);
            acc[t] = __builtin_amdgcn_mfma_f32_16x16x32_f16(af, bf, acc[t], 0, 0, 0);
        }
    }

    // epilogue: D layout col = l&15, row = 4*(l>>4)+r
    float aS[8], aD[8];
#pragma unroll
    for (int t = 0; t < 8; ++t) {
        aS[t] = attS[16 * t + bcol];
        aD[t] = attD[16 * t + bcol];
    }
#pragma unroll
    for (int r = 0; r < 4; ++r) {
        int n = n0 + wv * 16 + 4 * (l >> 4) + r;
        float ts[4], td[4];
#pragma unroll
        for (int h = 0; h < 4; ++h) {
            ts[h] = acc[2 * h][r] * aS[2 * h] + acc[2 * h + 1][r] * aS[2 * h + 1];
            td[h] = acc[2 * h][r] * aD[2 * h] + acc[2 * h + 1][r] * aD[2 * h + 1];
        }
#pragma unroll
        for (int off = 1; off <= 8; off <<= 1)
#pragma unroll
            for (int h = 0; h < 4; ++h) {
                ts[h] += __shfl_xor(ts[h], off, 64);
                td[h] += __shfl_xor(td[h], off, 64);
            }
        if (n < N) {
#pragma unroll
            for (int t = 0; t < 8; ++t)
                hx1h[(size_t)n * C1 + 16 * t + bcol] = __float2half(acc[t][r]);
            if (bcol == 0) {
#pragma unroll
                for (int h = 0; h < 4; ++h) {
                    as1[n * H1N + h] = ts[h];
                    ad1[n * H1N + h] = td[h];
                }
            }
        }
    }
}

// ---------------- CSR build pass C: partition edges into bucket order ----------------
__global__ void part_scatter(const int* __restrict__ src, const int* __restrict__ dst,
                             const int* __restrict__ bbase, int2* __restrict__ pedge,
                             int E, int chunk, int nbuk) {
    __shared__ int cur[NBUK_MAX];
    for (int t = threadIdx.x; t < nbuk; t += blockDim.x)
        cur[t] = bbase[(size_t)t * NBLK_P + blockIdx.x];
    __syncthreads();
    int lo = blockIdx.x * chunk, hi = min(lo + chunk, E);
    for (int i = lo + threadIdx.x; i < hi; i += blockDim.x) {
        int d = dst[i];
        int p = atomicAdd(&cur[d >> 8], 1);            // LDS atomic
        pedge[p] = make_int2(src[i], d);
    }
}

// ---------------- CSR build pass D: per-bucket fine CSR (256 nodes/bucket) ----------------
__global__ __launch_bounds__(256) void part_csr(
        const int2* __restrict__ pedge, const int* __restrict__ bbase,
        int* __restrict__ offsets, int* __restrict__ edge_src,
        int N, int E, int nbuk) {
    __shared__ int fcnt[256];
    __shared__ int fsc[256];
    int b = blockIdx.x;
    int t = threadIdx.x;
    int ebeg = bbase[(size_t)b * NBLK_P];
    int eend = (b + 1 < nbuk) ? bbase[(size_t)(b + 1) * NBLK_P] : E;
    int nbase = b << 8;
    fcnt[t] = 0;
    __syncthreads();
    for (int i = ebeg + t; i < eend; i += 256)
        atomicAdd(&fcnt[pedge[i].y - nbase], 1);       // LDS atomic
    __syncthreads();
    int v = fcnt[t];
    fsc[t] = v;
    __syncthreads();
    for (int off = 1; off < 256; off <<= 1) {
        int u = (t >= off) ? fsc[t - off] : 0;
        __syncthreads();
        fsc[t] += u;
        __syncthreads();
    }
    int goff = ebeg + fsc[t] - v;                      // global CSR start of node nbase+t
    int node = nbase + t;
    if (node < N) offsets[node] = goff;
    if (b == nbuk - 1 && t == 0) offsets[N] = E;
    __syncthreads();
    fcnt[t] = goff;                                    // reuse as cursor
    __syncthreads();
    for (int i = ebeg + t; i < eend; i += 256) {
        int2 e = pedge[i];
        int p = atomicAdd(&fcnt[e.y - nbase], 1);      // LDS atomic
        edge_src[p] = e.x;
    }
}

// ---------------- scan: generic hierarchical exclusive scan ----------------
__global__ void scan_partial(const int* __restrict__ counts, int* __restrict__ tilesums, int N) {
    __shared__ int red[SCAN_T];
    int t  = threadIdx.x;
    int i0 = blockIdx.x * SCAN_TILE + 2 * t;
    int s = 0;
    if (i0     < N) s += counts[i0];
    if (i0 + 1 < N) s += counts[i0 + 1];
    red[t] = s;
    __syncthreads();
    for (int off = SCAN_T / 2; off > 0; off >>= 1) {
        if (t < off) red[t] += red[t + off];
        __syncthreads();
    }
    if (t == 0) tilesums[blockIdx.x] = red[0];
}

__global__ void scan_tops(const int* __restrict__ tilesums, int* __restrict__ tilebase, int ntiles) {
    __shared__ int sh[SCAN_T];
    int t = threadIdx.x;
    int v = (t < ntiles) ? tilesums[t] : 0;
    sh[t] = v;
    __syncthreads();
    for (int off = 1; off < SCAN_T; off <<= 1) {
        int u = (t >= off) ? sh[t - off] : 0;
        __syncthreads();
        sh[t] += u;
        __syncthreads();
    }
    tilebase[t] = sh[t] - v;
}

__global__ void scan_final(const int* __restrict__ counts, const int* __restrict__ tilebase,
                           int* __restrict__ base, int N, int E) {
    __shared__ int sh[SCAN_T];
    int t  = threadIdx.x;
    int i0 = blockIdx.x * SCAN_TILE + 2 * t;
    int a   = (i0     < N) ? counts[i0]     : 0;
    int b   = (i0 + 1 < N) ? counts[i0 + 1] : 0;
    int tot = a + b;
    sh[t] = tot;
    __syncthreads();
    for (int off = 1; off < SCAN_T; off <<= 1) {
        int u = (t >= off) ? sh[t - off] : 0;
        __syncthreads();
        sh[t] += u;
        __syncthreads();
    }
    int excl = sh[t] - tot + tilebase[blockIdx.x];
    if (i0 < N)     base[i0]     = excl;
    if (i0 + 1 < N) base[i0 + 1] = excl + a;
    if (blockIdx.x == 0 && t == 0) base[N] = E;
}

// ---------------- layer 1 aggregate: no-max softmax, fp16 gather, fp16 x1 out ----------------
__global__ void agg1_kernel(const int* __restrict__ edge_src, const int* __restrict__ offsets,
                            const float* __restrict__ as1, const float* __restrict__ ad1,
                            const __half* __restrict__ hx1h, const float* __restrict__ b1,
                            __half* __restrict__ x1h, int N) {
    __shared__ int   ssh[4][64];
    __shared__ float esh[4][64][4];
    int wid  = threadIdx.x >> 6;
    int n    = (blockIdx.x * blockDim.x + threadIdx.x) >> 6;
    int lane = threadIdx.x & 63;
    if (n >= N) return;
    int hsel = lane >> 4;                    // head of cols (2l, 2l+1)
    const float4 ad4 = *(const float4*)(ad1 + 4 * n);
    int beg = offsets[n], end = offsets[n + 1];

    float den[4] = {0.f, 0.f, 0.f, 0.f};
    float acc0 = 0.f, acc1 = 0.f;

    for (int cb = beg; cb < end; cb += 64) {
        int j = cb + lane;
        bool valid = j < end;
        int s = valid ? edge_src[j] : 0;
        float e0 = 0.f, e1 = 0.f, e2 = 0.f, e3 = 0.f;
        if (valid) {
            const float4 a4 = *(const float4*)(as1 + 4 * s);
            float v0 = a4.x + ad4.x, v1 = a4.y + ad4.y;
            float v2 = a4.z + ad4.z, v3 = a4.w + ad4.w;
            v0 = v0 > 0.f ? v0 : 0.2f * v0;
            v1 = v1 > 0.f ? v1 : 0.2f * v1;
            v2 = v2 > 0.f ? v2 : 0.2f * v2;
            v3 = v3 > 0.f ? v3 : 0.2f * v3;
            e0 = __expf(v0); e1 = __expf(v1);
            e2 = __expf(v2); e3 = __expf(v3);
            den[0] += e0; den[1] += e1; den[2] += e2; den[3] += e3;
        }
        ssh[wid][lane] = s;
        *(float4*)&esh[wid][lane][0] = make_float4(e0, e1, e2, e3);

        int cnt = min(64, end - cb);
#pragma unroll 4
        for (int jj = 0; jj < cnt; ++jj) {
            int   sj = ssh[wid][jj];
            float w  = esh[wid][jj][hsel];
            const __half2* hr = (const __half2*)(hx1h + (size_t)sj * C1);
            float2 vf = __half22float2(hr[lane]);
            acc0 += w * vf.x;
            acc1 += w * vf.y;
        }
    }

#pragma unroll
    for (int off = 32; off > 0; off >>= 1)
#pragma unroll
        for (int h = 0; h < 4; ++h) den[h] += __shfl_xor(den[h], off, 64);

    float d = lane < 16 ? den[0] : lane < 32 ? den[1] : lane < 48 ? den[2] : den[3];
    float inv = 1.f / (d + 1e-16f);
    float2 bv = *(const float2*)(b1 + 2 * lane);
    float o0 = acc0 * inv + bv.x;
    float o1 = acc1 * inv + bv.y;
    o0 = o0 > 0.f ? o0 : (__expf(o0) - 1.f);   // ELU
    o1 = o1 > 0.f ? o1 : (__expf(o1) - 1.f);
    *(__half2*)&x1h[(size_t)n * C1 + 2 * lane] = __floats2half2_rn(o0, o1);
}

// ---------------- layer 2 GEMM: hx2 = x1 @ W2 (+ logits); fp16 in, fp16 out ----------------
__global__ __launch_bounds__(256) void gemm2_kernel(
        const __half* __restrict__ x1h, const float* __restrict__ W2,
        const float* __restrict__ attS, const float* __restrict__ attD,
        __half* __restrict__ hx2h, float* __restrict__ as2, float* __restrict__ ad2,
        int N) {
    __shared__ float xT[BK2][64 + 4];
    __shared__ float ws2[BK2][D2N];

    int tid = threadIdx.x;
    int tx  = tid & 15;
    int ty  = tid >> 4;
    int n0  = blockIdx.x * 64;

    float acc[4][4];
#pragma unroll
    for (int r = 0; r < 4; ++r)
#pragma unroll
        for (int c = 0; c < 4; ++c) acc[r][c] = 0.f;

    int lr = tid >> 2;                 // 0..63
    int lk = (tid & 3) * 8;            // 0,8,16,24 (8 halves = 16B)
    int xrow = n0 + lr; if (xrow >= N) xrow = N - 1;
    const __half* xptr = x1h + (size_t)xrow * C1;
    int kw = tid >> 4;
    int cw = tx * 4;

    for (int k0 = 0; k0 < C1; k0 += BK2) {
        f16x8 a = *reinterpret_cast<const f16x8*>(xptr + k0 + lk);
        float4 w0 = *(const float4*)(W2 + (size_t)(k0 + kw     ) * D2N + cw);
        float4 w1 = *(const float4*)(W2 + (size_t)(k0 + kw + 16) * D2N + cw);
        __syncthreads();
#pragma unroll
        for (int j = 0; j < 8; ++j) xT[lk + j][lr] = (float)a[j];
        *(float4*)&ws2[kw     ][cw] = w0;
        *(float4*)&ws2[kw + 16][cw] = w1;
        __syncthreads();
#pragma unroll
        for (int k = 0; k < BK2; ++k) {
            float4 xa = *(const float4*)&xT[k][ty * 4];
            float4 wv = *(const float4*)&ws2[k][tx * 4];
            float xr[4] = {xa.x, xa.y, xa.z, xa.w};
            float wc[4] = {wv.x, wv.y, wv.z, wv.w};
#pragma unroll
            for (int r = 0; r < 4; ++r)
#pragma unroll
                for (int c = 0; c < 4; ++c) acc[r][c] += xr[r] * wc[c];
        }
    }

    const float4 asv = *(const float4*)(attS + tx * 4);
    const float4 adv = *(const float4*)(attD + tx * 4);
#pragma unroll
    for (int r = 0; r < 4; ++r) {
        int n = n0 + ty * 4 + r;
        float ts = acc[r][0] * asv.x + acc[r][1] * asv.y + acc[r][2] * asv.z + acc[r][3] * asv.w;
        float td = acc[r][0] * adv.x + acc[r][1] * adv.y + acc[r][2] * adv.z + acc[r][3] * adv.w;
        ts += __shfl_xor(ts, 1); td += __shfl_xor(td, 1);
        ts += __shfl_xor(ts, 2); td += __shfl_xor(td, 2);
        ts += __shfl_xor(ts, 4); td += __shfl_xor(td, 4);
        ts += __shfl_xor(ts, 8); td += __shfl_xor(td, 8);
        if (n < N) {
            *(__half2*)&hx2h[(size_t)n * D2N + tx * 4]     = __floats2half2_rn(acc[r][0], acc[r][1]);
            *(__half2*)&hx2h[(size_t)n * D2N + tx * 4 + 2] = __floats2half2_rn(acc[r][2], acc[r][3]);
            if (tx == 0) { as2[n] = ts; ad2[n] = td; }
        }
    }
}

// ---------------- layer 2 aggregate: no-max softmax, fp16 gather, last num_new nodes ----------------
__global__ void agg2_kernel(const int* __restrict__ edge_src, const int* __restrict__ offsets,
                            const float* __restrict__ as2, const float* __restrict__ ad2,
                            const __half* __restrict__ hx2h, const float* __restrict__ b2,
                            float* __restrict__ out, int N, int num_new) {
    __shared__ int   ssh[4][64];
    __shared__ float esh[4][64];
    int wid  = threadIdx.x >> 6;
    int w    = (blockIdx.x * blockDim.x + threadIdx.x) >> 6;
    int lane = threadIdx.x & 63;
    if (w >= num_new) return;
    int n = N - num_new + w;
    float adn = ad2[n];
    int beg = offsets[n], end = offsets[n + 1];

    float den = 0.f, acc = 0.f;
    for (int cb = beg; cb < end; cb += 64) {
        int j = cb + lane;
        bool valid = j < end;
        int s = valid ? edge_src[j] : 0;
        float e = 0.f;
        if (valid) {
            float v = as2[s] + adn;
            v = v > 0.f ? v : 0.2f * v;
            e = __expf(v);
            den += e;
        }
        ssh[wid][lane] = s;
        esh[wid][lane] = e;

        int cnt = min(64, end - cb);
#pragma unroll 4
        for (int jj = 0; jj < cnt; ++jj) {
            int   sj = ssh[wid][jj];
            float wj = esh[wid][jj];
            acc += wj * __half2float(hx2h[(size_t)sj * D2N + lane]);
        }
    }
#pragma unroll
    for (int off = 32; off > 0; off >>= 1) den += __shfl_xor(den, off, 64);
    out[(size_t)w * D2N + lane] = acc / (den + 1e-16f) + b2[lane];
}

// ---------------- launch ----------------
extern "C" void kernel_launch(void* const* d_in, const int* in_sizes, int n_in,
                              void* d_out, int out_size, void* d_ws, size_t ws_size,
                              hipStream_t stream) {
    const float* x      = (const float*)d_in[0];
    const int*   src    = (const int*)d_in[1];
    const int*   dst    = (const int*)d_in[2];
    const float* W1     = (const float*)d_in[3];
    const float* attS1  = (const float*)d_in[4];
    const float* attD1  = (const float*)d_in[5];
    const float* b1     = (const float*)d_in[6];
    const float* W2     = (const float*)d_in[7];
    const float* attS2  = (const float*)d_in[8];
    const float* attD2  = (const float*)d_in[9];
    const float* b2     = (const float*)d_in[10];

    const int N = in_sizes[0] / F_IN;   // 50000
    const int E = in_sizes[1];          // 1000000
    const int num_new = out_size / D2N; // 10000
    const int ngemm  = (N + 63) / 64;                     // 782
    const int nbuk   = (N + 255) >> 8;                    // 196
    const int M      = nbuk * NBLK_P;                     // 50176
    const int ntilesM = (M + SCAN_TILE - 1) / SCAN_TILE;  // 98
    const int chunk  = (E + NBLK_P - 1) / NBLK_P;         // 3907

    // workspace carve-up
    __half* hx1h = (__half*)d_ws;                        // N*128 halves
    __half* x1h  = hx1h + (size_t)N * C1;                // N*128 halves
    __half* hx2h = x1h  + (size_t)N * C1;                // N*64 halves
    float* as1 = (float*)(hx2h + (size_t)N * D2N);       // N*4
    float* ad1 = as1 + (size_t)N * H1N;                  // N*4
    float* as2 = ad1 + (size_t)N * H1N;                  // N
    float* ad2 = as2 + N;                                // N
    int* bcounts  = (int*)(ad2 + N);                     // M
    int* bbase    = bcounts + M;                         // M+1
    int* offsets  = bbase + M + 1;                       // N+1
    int* tilesums = offsets + N + 1;                     // 256
    int* tilebase = tilesums + 256;                      // 256
    int* edge_src = tilebase + 256;                      // E
    int2* pedge   = (int2*)(edge_src + E);               // E int2
    __half* W1T   = (__half*)(pedge + E);                // 128*256 halves

    float* out = (float*)d_out;

    hipLaunchKernelGGL(w1_transpose, dim3(C1), dim3(256), 0, stream, W1, W1T);
    hipLaunchKernelGGL(gemm1_hist_kernel, dim3(ngemm + NBLK_P), dim3(256), 0, stream,
                       x, W1T, attS1, attD1, hx1h, as1, ad1, N,
                       dst, bcounts, E, chunk, nbuk, ngemm);
    hipLaunchKernelGGL(scan_partial, dim3(ntilesM), dim3(SCAN_T), 0, stream, bcounts, tilesums, M);
    hipLaunchKernelGGL(scan_tops, dim3(1), dim3(SCAN_T), 0, stream, tilesums, tilebase, ntilesM);
    hipLaunchKernelGGL(scan_final, dim3(ntilesM), dim3(SCAN_T), 0, stream,
                       bcounts, tilebase, bbase, M, E);
    hipLaunchKernelGGL(part_scatter, dim3(NBLK_P), dim3(256), 0, stream,
                       src, dst, bbase, pedge, E, chunk, nbuk);
    hipLaunchKernelGGL(part_csr, dim3(nbuk), dim3(256), 0, stream,
                       pedge, bbase, offsets, edge_src, N, E, nbuk);
    hipLaunchKernelGGL(agg1_kernel, dim3((N + 3) / 4), dim3(256), 0, stream,
                       edge_src, offsets, as1, ad1, hx1h, b1, x1h, N);
    hipLaunchKernelGGL(gemm2_kernel, dim3((N + 63) / 64), dim3(256), 0, stream,
                       x1h, W2, attS2, attD2, hx2h, as2, ad2, N);
    hipLaunchKernelGGL(agg2_kernel, dim3((num_new + 3) / 4), dim3(256), 0, stream,
                       edge_src, offsets, as2, ad2, hx2h, b2, out, N, num_new);
}